// Round 1
// 1756.822 us; speedup vs baseline: 1.0163x; 1.0163x over previous
//
#include <hip/hip_runtime.h>
#include <hip/hip_bf16.h>
#include <stdint.h>

#define N_NODES 16384
#define HDIM 64
#define NM (N_NODES * HDIM)   // 1048576
#define KS 8                  // K-split for the big GEMM
#define BM 128
#define BK 128
#define KRANGE (N_NODES / KS) // 2048
#define NTILES (KRANGE / BK)  // 16

typedef __attribute__((ext_vector_type(8))) short short8;
typedef __attribute__((ext_vector_type(16))) float floatx16;

__device__ inline unsigned short f2bf(float x) {
    union { float f; unsigned u; } v; v.f = x;
    unsigned r = v.u + 0x7fff + ((v.u >> 16) & 1);
    return (unsigned short)(r >> 16);
}

// load 8 consecutive fp32 and convert to 8 bf16
__device__ inline short8 cvt8(const float* __restrict__ p) {
    float4 a = *(const float4*)p;
    float4 b = *(const float4*)(p + 4);
    short8 r;
    r[0] = (short)f2bf(a.x); r[1] = (short)f2bf(a.y);
    r[2] = (short)f2bf(a.z); r[3] = (short)f2bf(a.w);
    r[4] = (short)f2bf(b.x); r[5] = (short)f2bf(b.y);
    r[6] = (short)f2bf(b.z); r[7] = (short)f2bf(b.w);
    return r;
}

template <bool HF32>
__device__ inline short8 ldh(const unsigned short* __restrict__ hbf,
                             const float* __restrict__ hf32, size_t off) {
    if constexpr (HF32) return cvt8(hf32 + off);
    else return *(const short8*)(hbf + off);
}

// ---------------- fused prep: blocks [0,128) compute HrT2, blocks [128,256) compute Root ----
// HrT2 tiled: element (k=j, n=f) at ((k>>3)*64 + n)*8 + (k&7) shorts.
// Hr[j][f] = sum_c W_rel[f][c] * h[j][c];  Root[j][f] = sum_c h[j][c] * W_root[f][c]
// block 256 = 4 waves; wave w: j rows [j0, j0+32)
template <bool HF32>
__global__ __launch_bounds__(256) void prep_both(const float* __restrict__ Wrel,
                                                 const float* __restrict__ Wroot,
                                                 const unsigned short* __restrict__ hbf,
                                                 const float* __restrict__ hf32,
                                                 unsigned short* __restrict__ HrT2,
                                                 float* __restrict__ Root, int Cin) {
    int t = threadIdx.x, lane = t & 63, w = t >> 6;
    int bx = blockIdx.x & 127;
    int j0 = bx * 128 + 32 * w;
    int n = lane & 31, q = lane >> 5;
    floatx16 acc0 = {}, acc1 = {};
    if (blockIdx.x < 128) {
        // Hr role: B[k=j][n..] from h, A[m=f][k=c] from W_rel
        for (int c0 = 0; c0 < Cin; c0 += 16) {
            int k = c0 + 8 * q;
            short8 b  = ldh<HF32>(hbf, hf32, (size_t)(j0 + n) * Cin + k);
            short8 a0 = cvt8(Wrel + (size_t)n * Cin + k);
            short8 a1 = cvt8(Wrel + (size_t)(n + 32) * Cin + k);
            acc0 = __builtin_amdgcn_mfma_f32_32x32x16_bf16(a0, b, acc0, 0, 0, 0);
            acc1 = __builtin_amdgcn_mfma_f32_32x32x16_bf16(a1, b, acc1, 0, 0, 0);
        }
        int j = j0 + n;
        size_t jb = (size_t)(j >> 3) * 512 + (j & 7);
#pragma unroll
        for (int r = 0; r < 16; ++r) {
            int f = (r & 3) + 8 * (r >> 2) + 4 * q;     // C/D row within 32-tile = feature
            HrT2[jb + (size_t)f * 8]        = f2bf(acc0[r]);
            HrT2[jb + (size_t)(f + 32) * 8] = f2bf(acc1[r]);
        }
    } else {
        // Root role: A[m=j][k=c] from h, B[k=c][n=f] from W_root
        for (int c0 = 0; c0 < Cin; c0 += 16) {
            int k = c0 + 8 * q;
            short8 a  = ldh<HF32>(hbf, hf32, (size_t)(j0 + n) * Cin + k);
            short8 b0 = cvt8(Wroot + (size_t)n * Cin + k);
            short8 b1 = cvt8(Wroot + (size_t)(n + 32) * Cin + k);
            acc0 = __builtin_amdgcn_mfma_f32_32x32x16_bf16(a, b0, acc0, 0, 0, 0);
            acc1 = __builtin_amdgcn_mfma_f32_32x32x16_bf16(a, b1, acc1, 0, 0, 0);
        }
#pragma unroll
        for (int r = 0; r < 16; ++r) {
            int jrow = j0 + (r & 3) + 8 * (r >> 2) + 4 * q;
            Root[(size_t)jrow * HDIM + n]      = acc0[r];
            Root[(size_t)jrow * HDIM + 32 + n] = acc1[r];
        }
    }
}

// ---------------- layer-0 big GEMM: partial[ky] = adjT(krange) . Hr(krange) ----------------
// Also (optionally) writes adj_bf: bf16 transposed adj in MFMA-fragment tiled layout.
// Tile T = bx*128 + (kb>>7); within tile element (m, k) at (k>>3)*1024 + m*8 + (k&7) shorts.
__global__ __launch_bounds__(256, 3) void agg_cvt(const float* __restrict__ adj,
                                                  const unsigned short* __restrict__ HrT2,
                                                  float* __restrict__ part,
                                                  unsigned short* __restrict__ adj_bf,
                                                  int write_copy) {
    __shared__ unsigned short As[BM * BK];  // elem (m,k) at m*128 + ((k>>3)^(m&7))*8 + (k&7)
    int t = threadIdx.x, lane = t & 63, w = t >> 6;
    int m0 = blockIdx.x * BM;
    int kbeg = blockIdx.y * KRANGE;
    int kg = t >> 3;        // 0..31
    int mgb = t & 7;
    int n = lane & 31, q = lane >> 5;
    int mrow = 32 * w + n;
    int mbase = mrow << 7;
    int msw = mrow & 7;
    floatx16 acc0 = {}, acc1 = {};

    for (int kt = 0; kt < NTILES; ++kt) {
        int kb = kbeg + kt * BK;
        __syncthreads();   // As safe to overwrite
#pragma unroll
        for (int r = 0; r < 4; ++r) {
            int mg = mgb + 8 * r;  // 0..31
            const float* src = adj + (size_t)(kb + 4 * kg) * N_NODES + m0 + 4 * mg;
            float vv[4][4];
#pragma unroll
            for (int rr = 0; rr < 4; ++rr)
                *(float4*)&vv[rr][0] = *(const float4*)(src + (size_t)rr * N_NODES);
#pragma unroll
            for (int i = 0; i < 4; ++i) {
                int m = 4 * mg + i;
                ushort4 o;
                o.x = f2bf(vv[0][i]); o.y = f2bf(vv[1][i]);
                o.z = f2bf(vv[2][i]); o.w = f2bf(vv[3][i]);
                *(ushort4*)&As[(m << 7) + (((kg >> 1) ^ (m & 7)) << 3) + ((kg & 1) << 2)] = o;
            }
        }
        __syncthreads();
        const unsigned short* bp = HrT2 + ((size_t)(kb >> 3) << 9);
#pragma unroll
        for (int s = 0; s < 8; ++s) {
            int g = 2 * s + q;
            short8 a  = *(const short8*)&As[mbase + ((g ^ msw) << 3)];
            short8 b0 = *(const short8*)(bp + (size_t)g * 512 + n * 8);
            short8 b1 = *(const short8*)(bp + (size_t)g * 512 + (n + 32) * 8);
            acc0 = __builtin_amdgcn_mfma_f32_32x32x16_bf16(a, b0, acc0, 0, 0, 0);
            acc1 = __builtin_amdgcn_mfma_f32_32x32x16_bf16(a, b1, acc1, 0, 0, 0);
        }
        if (write_copy) {
            unsigned short* dst = adj_bf + ((size_t)(blockIdx.x * 128 + (kb >> 7)) << 14);
#pragma unroll
            for (int p = 0; p < 8; ++p) {
                int I = p * 256 + t;          // 16B chunk index within tile
                int m = I & 127, g = I >> 7;
                short8 v = *(const short8*)&As[(m << 7) + ((g ^ (m & 7)) << 3)];
                *(short8*)(dst + (size_t)I * 8) = v;
            }
        }
    }
    float* P = part + (size_t)blockIdx.y * NM;
#pragma unroll
    for (int r = 0; r < 16; ++r) {
        int row = (r & 3) + 8 * (r >> 2) + 4 * q;
        size_t off = (size_t)(m0 + 32 * w + row) * HDIM;
        P[off + n]      = acc0[r];
        P[off + 32 + n] = acc1[r];
    }
}

// ---------------- layers 1-2 big GEMM: reads pre-transposed bf16 adj, no LDS, no barriers ----------------
__global__ __launch_bounds__(256, 4) void agg_bf(const unsigned short* __restrict__ adj_bf,
                                                 const unsigned short* __restrict__ HrT2,
                                                 float* __restrict__ part) {
    int t = threadIdx.x, lane = t & 63, w = t >> 6;
    int m0 = blockIdx.x * BM;
    int n = lane & 31, q = lane >> 5;
    int mrow = 32 * w + n;
    floatx16 acc0 = {}, acc1 = {};
    for (int kt = 0; kt < NTILES; ++kt) {
        int kb = blockIdx.y * KRANGE + kt * BK;
        const unsigned short* tp = adj_bf + ((size_t)(blockIdx.x * 128 + (kb >> 7)) << 14);
        const unsigned short* bp = HrT2 + ((size_t)(kb >> 3) << 9);
#pragma unroll
        for (int s = 0; s < 8; ++s) {
            int g = 2 * s + q;
            short8 a  = *(const short8*)(tp + (size_t)g * 1024 + mrow * 8);
            short8 b0 = *(const short8*)(bp + (size_t)g * 512 + n * 8);
            short8 b1 = *(const short8*)(bp + (size_t)g * 512 + (n + 32) * 8);
            acc0 = __builtin_amdgcn_mfma_f32_32x32x16_bf16(a, b0, acc0, 0, 0, 0);
            acc1 = __builtin_amdgcn_mfma_f32_32x32x16_bf16(a, b1, acc1, 0, 0, 0);
        }
    }
    float* P = part + (size_t)blockIdx.y * NM;
#pragma unroll
    for (int r = 0; r < 16; ++r) {
        int row = (r & 3) + 8 * (r >> 2) + 4 * q;
        size_t off = (size_t)(m0 + 32 * w + row) * HDIM;
        P[off + n]      = acc0[r];
        P[off + 32 + n] = acc1[r];
    }
}

// ---------------- epilogue: sum partials + Root + bias, relu, write (float4/thread) ----------
__global__ __launch_bounds__(256) void epilogue(const float* __restrict__ part,
                                                const float* __restrict__ Root,
                                                const float* __restrict__ brel,
                                                unsigned short* __restrict__ out_bf,
                                                float* __restrict__ out_f32, int write_f32) {
    int base = (blockIdx.x * 256 + threadIdx.x) * 4;
    float4 v = *(const float4*)(Root + base);
    float4 bb = *(const float4*)(brel + (base & 63));
    v.x += bb.x; v.y += bb.y; v.z += bb.z; v.w += bb.w;
#pragma unroll
    for (int i = 0; i < KS; ++i) {
        float4 p = *(const float4*)(part + (size_t)i * NM + base);
        v.x += p.x; v.y += p.y; v.z += p.z; v.w += p.w;
    }
    v.x = fmaxf(v.x, 0.f); v.y = fmaxf(v.y, 0.f);
    v.z = fmaxf(v.z, 0.f); v.w = fmaxf(v.w, 0.f);
    if (write_f32) {
        *(float4*)(out_f32 + base) = v;
    } else {
        ushort4 o;
        o.x = f2bf(v.x); o.y = f2bf(v.y); o.z = f2bf(v.z); o.w = f2bf(v.w);
        *(ushort4*)(out_bf + base) = o;
    }
}

extern "C" void kernel_launch(void* const* d_in, const int* in_sizes, int n_in,
                              void* d_out, int out_size, void* d_ws, size_t ws_size,
                              hipStream_t stream) {
    const float* X       = (const float*)d_in[0];
    const float* adj     = (const float*)d_in[1];
    const float* W_rel0  = (const float*)d_in[2];
    const float* b_rel0  = (const float*)d_in[3];
    const float* W_root0 = (const float*)d_in[4];
    const float* W_rel1  = (const float*)d_in[5];
    const float* b_rel1  = (const float*)d_in[6];
    const float* W_root1 = (const float*)d_in[7];
    const float* W_rel2  = (const float*)d_in[8];
    const float* b_rel2  = (const float*)d_in[9];
    const float* W_root2 = (const float*)d_in[10];

    // workspace layout
    unsigned short* hbfA = (unsigned short*)d_ws;          // NM bf16 = 2 MB (h2)
    unsigned short* hbfB = hbfA + (size_t)NM;              // 2 MB (h1)
    unsigned short* HrT2 = hbfB + (size_t)NM;              // 2 MB, tiled layout
    float* Root = (float*)(HrT2 + (size_t)NM);             // 4 MB
    float* part = Root + (size_t)NM;                       // KS * 4 MB = 32 MB
    unsigned short* adj_bf = (unsigned short*)(part + (size_t)KS * NM);  // 512 MB
    size_t need = (size_t)((char*)adj_bf - (char*)d_ws) + (size_t)N_NODES * N_NODES * 2;
    int use_copy = (ws_size >= need) ? 1 : 0;

    dim3 blk(256);
    dim3 agrid(N_NODES / BM, KS);
    int egrid = NM / (256 * 4);

    // ---- layer 0 (Cin = 256, h = X fp32 read directly) ----
    prep_both<true><<<256, blk, 0, stream>>>(W_rel0, W_root0, nullptr, X, HrT2, Root, 256);
    agg_cvt<<<agrid, blk, 0, stream>>>(adj, HrT2, part, adj_bf, use_copy);
    epilogue<<<egrid, blk, 0, stream>>>(part, Root, b_rel0, hbfB, nullptr, 0);

    // ---- layer 1 (Cin = 64) ----
    prep_both<false><<<256, blk, 0, stream>>>(W_rel1, W_root1, hbfB, nullptr, HrT2, Root, 64);
    if (use_copy) agg_bf<<<agrid, blk, 0, stream>>>(adj_bf, HrT2, part);
    else          agg_cvt<<<agrid, blk, 0, stream>>>(adj, HrT2, part, adj_bf, 0);
    epilogue<<<egrid, blk, 0, stream>>>(part, Root, b_rel1, hbfA, nullptr, 0);

    // ---- layer 2 (Cin = 64) ----
    prep_both<false><<<256, blk, 0, stream>>>(W_rel2, W_root2, hbfA, nullptr, HrT2, Root, 64);
    if (use_copy) agg_bf<<<agrid, blk, 0, stream>>>(adj_bf, HrT2, part);
    else          agg_cvt<<<agrid, blk, 0, stream>>>(adj, HrT2, part, adj_bf, 0);
    epilogue<<<egrid, blk, 0, stream>>>(part, Root, b_rel2, nullptr, (float*)d_out, 1);
}